// Round 8
// baseline (934.575 us; speedup 1.0000x reference)
//
#include <hip/hip_runtime.h>
#include <stdint.h>

#define TT 512

typedef __fp16   f16x8  __attribute__((ext_vector_type(8)));
typedef float    f32x4  __attribute__((ext_vector_type(4)));
typedef __fp16   fp16x2 __attribute__((ext_vector_type(2)));
typedef uint32_t u32x2  __attribute__((ext_vector_type(2)));

__device__ __forceinline__ float sigm(float x) {
    float e = __builtin_amdgcn_exp2f(-1.4426950408889634f * x);
    return __builtin_amdgcn_rcpf(1.0f + e);
}
__device__ __forceinline__ f32x4 mfma16(f16x8 a, f16x8 b, f32x4 c) {
    return __builtin_amdgcn_mfma_f32_16x16x32_f16(a, b, c, 0, 0, 0);
}
__device__ __forceinline__ uint32_t pkf16(float a, float b) {
    fp16x2 h = __builtin_amdgcn_cvt_pkrtz(a, b);
    return __builtin_bit_cast(uint32_t, h);
}

#define REP16(M) M(0)M(1)M(2)M(3)M(4)M(5)M(6)M(7)M(8)M(9)M(10)M(11)M(12)M(13)M(14)M(15)

// A-operand gather (weights TRANSPOSED, z^T form): A[m=16T+l15][k=32F+8q+j] = SRC[k][16T+l15]
#define GA(SRC, T, F) (f16x8){ \
  (__fp16)(SRC)[(32*(F)+8*quad+0)*256 + 16*(T)+l15], \
  (__fp16)(SRC)[(32*(F)+8*quad+1)*256 + 16*(T)+l15], \
  (__fp16)(SRC)[(32*(F)+8*quad+2)*256 + 16*(T)+l15], \
  (__fp16)(SRC)[(32*(F)+8*quad+3)*256 + 16*(T)+l15], \
  (__fp16)(SRC)[(32*(F)+8*quad+4)*256 + 16*(T)+l15], \
  (__fp16)(SRC)[(32*(F)+8*quad+5)*256 + 16*(T)+l15], \
  (__fp16)(SRC)[(32*(F)+8*quad+6)*256 + 16*(T)+l15], \
  (__fp16)(SRC)[(32*(F)+8*quad+7)*256 + 16*(T)+l15] }

// Named scalars only (R1-R3: arrays -> SROA scratch). U/Wx A-frags + f32 bias resident.
#define DECLT(T) f16x8 uA##T##_0, uA##T##_1, wA##T##_0, wA##T##_1; f32x4 bias##T;
#define LOADT(T) { \
  uA##T##_0 = GA(Uw, T, 0); uA##T##_1 = GA(Uw, T, 1); \
  bias##T = (f32x4){ bw_[16*(T)+4*quad+0], bw_[16*(T)+4*quad+1], \
                     bw_[16*(T)+4*quad+2], bw_[16*(T)+4*quad+3] }; \
  if (l > 0) { wA##T##_0 = GA(Wsrc, T, 0); wA##T##_1 = GA(Wsrc, T, 1); } \
  else { /* wave 0: stash fp32 Wx0 column scalars in the (otherwise unused) wA regs */ \
    wA##T##_0 = __builtin_bit_cast(f16x8, (f32x4){ Wx0[16*(T)+4*quad+0], Wx0[16*(T)+4*quad+1], \
                                                   Wx0[16*(T)+4*quad+2], Wx0[16*(T)+4*quad+3] }); \
    wA##T##_1 = wA##T##_0; } }

#define DECLA(T) f32x4 acc##T;
// bias enters as the C-operand of the first MFMA (no per-step mov cost)
#define MM4(T) { f32x4 a_ = mfma16(uA##T##_0, hB0, bias##T); \
  a_ = mfma16(uA##T##_1, hB1, a_); \
  a_ = mfma16(wA##T##_0, xB0, a_); \
  a_ = mfma16(wA##T##_1, xB1, a_); \
  acc##T = a_; }
#define MM0(T) { f32x4 a_ = mfma16(uA##T##_0, hB0, bias##T); \
  a_ = mfma16(uA##T##_1, hB1, a_); \
  a_ += __builtin_bit_cast(f32x4, wA##T##_0) * xv4; \
  acc##T = a_; }

// D layout: m = zr = 16T + 4*quad + r, n = row = l15. Gates: zr = u + 64g -> tiles T0,T0+4,T0+8,T0+12
#define GATE4(T0, TF, TG, TO) { \
  f32x4 hv_; \
  _Pragma("unroll") \
  for (int r = 0; r < 4; ++r) { \
    float cv = sigm(acc##TF[r]) * cst##T0[r] + sigm(acc##T0[r]) * fmaxf(acc##TG[r], 0.f); \
    cst##T0[r] = cv; \
    hv_[r] = sigm(acc##TO[r]) * fmaxf(cv, 0.f); \
  } \
  u32x2 pv_ = { pkf16(hv_[0], hv_[1]), pkf16(hv_[2], hv_[3]) }; \
  *(u32x2*)(hwl + 16*(T0)) = pv_; \
  if (l == 3 && t == TT - 1) hK##T0 = hv_; }

// 64 blocks x 256 threads; block = 16 batch rows; 4 waves = 4 layers (whole layer per wave).
// Recurrence is INTRA-WAVE (lgkm-ordered LDS roundtrip, no barrier). Layer handoff via
// 4-deep slot buffer + per-wave progress counters (spin flags) -> zero barriers in the loop.
// waves_per_eu(1,1): 512-VGPR budget for ~450 thread-resident weight/bias regs.
__global__ __launch_bounds__(256)
__attribute__((amdgpu_waves_per_eu(1, 1)))
void lstm_wavepipe(
    const float* __restrict__ x,
    const float* __restrict__ Wx0, const float* __restrict__ U0, const float* __restrict__ b0,
    const float* __restrict__ Wx1, const float* __restrict__ U1, const float* __restrict__ b1,
    const float* __restrict__ Wx2, const float* __restrict__ U2, const float* __restrict__ b2,
    const float* __restrict__ Wx3, const float* __restrict__ U3, const float* __restrict__ b3,
    const float* __restrict__ Wd,  const float* __restrict__ bd,
    float* __restrict__ out)
{
    // dynamic LDS (dwords): hbuf f16 [0,9216) | x_s f32 [9216,17920) | flags [17920,17924)
    extern __shared__ uint32_t smem[];
    __fp16*       hbuf = (__fp16*)smem;            // [l][slot4][row 16][unit 64 pad 72] f16
    float*        x_s  = (float*)(smem + 9216);    // [t][17] padded
    volatile int* vf   = (volatile int*)(smem + 17920);

    const int tid  = threadIdx.x;
    const int lane = tid & 63;
    const int l15  = lane & 15;
    const int quad = lane >> 4;
    const int l    = tid >> 6;                     // wave = layer
    const int b0i  = blockIdx.x * 16;

    // ---- staging ----
    for (int i = tid; i < 9216; i += 256) smem[i] = 0;   // zero all h slots
    if (tid < 4) vf[tid] = 0;
    for (int i = tid; i < 16 * TT; i += 256) {
        int row = i >> 9, t_ = i & (TT - 1);
        x_s[t_ * 17 + row] = x[(b0i + row) * TT + t_];
    }

    const float* Uw   = (l == 0) ? U0 : (l == 1) ? U1 : (l == 2) ? U2 : U3;
    const float* bw_  = (l == 0) ? b0 : (l == 1) ? b1 : (l == 2) ? b2 : b3;
    const float* Wsrc = (l == 1) ? Wx1 : (l == 2) ? Wx2 : (l == 3) ? Wx3 : U0;

    REP16(DECLT)
    REP16(LOADT)

    f32x4 cst0 = {0,0,0,0}, cst1 = {0,0,0,0}, cst2 = {0,0,0,0}, cst3 = {0,0,0,0};
    f32x4 hK0 = {0,0,0,0}, hK1 = {0,0,0,0}, hK2 = {0,0,0,0}, hK3 = {0,0,0,0};

    __fp16* hb_l   = hbuf + l * 4608;              // own layer buffer (4 slots x 1152)
    __fp16* hb_in  = hbuf + (l > 0 ? (l - 1) * 4608 : 0);

    __syncthreads();                               // the only barrier

    for (int t = 0; t < TT; ++t) {
        const int sr = (t - 1) & 3, sw = t & 3;

        // own h[t-1]: B[k=unit=32F+8q+j][n=row=l15] — self-written, lgkm-ordered
        const __fp16* hown = hb_l + sr * 1152 + l15 * 72 + 8 * quad;
        f16x8 hB0 = *(const f16x8*)(hown);
        f16x8 hB1 = *(const f16x8*)(hown + 32);

        // back-pressure: writing slot sw overwrites h[t-4]; consumer must be past t-4
        if (l < 3) { while (vf[l + 1] < t - 3) ; }
        // producer-ready: need h^(l-1)[t]
        if (l > 0) { while (vf[l - 1] < t + 1) ; }
        __threadfence_block();                     // acquire

        REP16(DECLA)
        if (l > 0) {
            const __fp16* hin = hb_in + sw * 1152 + l15 * 72 + 8 * quad;
            f16x8 xB0 = *(const f16x8*)(hin);
            f16x8 xB1 = *(const f16x8*)(hin + 32);
            REP16(MM4)
        } else {
            float xv = x_s[t * 17 + l15];
            f32x4 xv4 = {xv, xv, xv, xv};
            REP16(MM0)
        }

        // gates + publish h (lane holds row=l15, units 16*T0+4*quad+r)
        __fp16* hwl = hb_l + sw * 1152 + l15 * 72 + 4 * quad;
        GATE4(0, 4,  8, 12)
        GATE4(1, 5,  9, 13)
        GATE4(2, 6, 10, 14)
        GATE4(3, 7, 11, 15)

        __threadfence_block();                     // release (drain h writes + x reads)
        vf[l] = t + 1;
    }

    // dense epilogue: wave 3 holds h[511] in hK regs (f32, pre-quant)
    if (l == 3) {
        float p = 0.f;
        #define EPI(T0) { f32x4 wdv = (f32x4){ Wd[16*(T0)+4*quad+0], Wd[16*(T0)+4*quad+1], \
                                               Wd[16*(T0)+4*quad+2], Wd[16*(T0)+4*quad+3] }; \
            p += hK##T0[0]*wdv[0] + hK##T0[1]*wdv[1] + hK##T0[2]*wdv[2] + hK##T0[3]*wdv[3]; }
        EPI(0) EPI(1) EPI(2) EPI(3)
        p += __shfl_down(p, 32, 64);
        p += __shfl_down(p, 16, 64);
        if (lane < 16) out[b0i + lane] = p + bd[0];
    }
}

extern "C" void kernel_launch(void* const* d_in, const int* in_sizes, int n_in,
                              void* d_out, int out_size, void* d_ws, size_t ws_size,
                              hipStream_t stream) {
    const float* x   = (const float*)d_in[0];
    const float* Wx0 = (const float*)d_in[1];
    const float* U0  = (const float*)d_in[2];
    const float* b0  = (const float*)d_in[3];
    const float* Wx1 = (const float*)d_in[4];
    const float* U1  = (const float*)d_in[5];
    const float* b1  = (const float*)d_in[6];
    const float* Wx2 = (const float*)d_in[7];
    const float* U2  = (const float*)d_in[8];
    const float* b2  = (const float*)d_in[9];
    const float* Wx3 = (const float*)d_in[10];
    const float* U3  = (const float*)d_in[11];
    const float* b3  = (const float*)d_in[12];
    const float* Wd  = (const float*)d_in[13];
    const float* bd  = (const float*)d_in[14];
    float* out = (float*)d_out;

    static const int kLds = 17924 * 4;   // 71696 B dynamic LDS
    (void)hipFuncSetAttribute((const void*)lstm_wavepipe,
                              hipFuncAttributeMaxDynamicSharedMemorySize, kLds);
    hipLaunchKernelGGL(lstm_wavepipe, dim3(64), dim3(256), kLds, stream,
                       x, Wx0, U0, b0, Wx1, U1, b1, Wx2, U2, b2, Wx3, U3, b3,
                       Wd, bd, out);
}